// Round 7
// baseline (640.376 us; speedup 1.0000x reference)
//
#include <hip/hip_runtime.h>
#include <stdint.h>

// ---- problem constants ----
#define D_MODEL  2048
#define N_INTER  1408
#define SH_INTER 2816
#define T_TOK    2048
#define NSLOT    (T_TOK * 4)
#define MIB(x)   ((size_t)(x) << 20)

typedef __attribute__((ext_vector_type(8))) short bf16x8;
typedef __attribute__((ext_vector_type(4))) float f32x4;

__device__ __forceinline__ unsigned short f2bf(float f){
  unsigned int b = __builtin_bit_cast(unsigned int, f);
  b = (b + 0x7FFFu + ((b >> 16) & 1u)) >> 16;   // RNE, finite inputs
  return (unsigned short)b;
}
__device__ __forceinline__ float bf2f(unsigned short h){
  unsigned int b = ((unsigned int)h) << 16;
  return __builtin_bit_cast(float, b);
}

// async global->LDS, 16B per lane; LDS dest = wave-uniform base + lane*16
#define GLOAD16(gp, lp) __builtin_amdgcn_global_load_lds( \
    (const __attribute__((address_space(1))) unsigned int*)(gp), \
    (__attribute__((address_space(3))) unsigned int*)(lp), 16, 0, 0)

// ---------------- fp32 -> bf16 streaming convert ----------------
__global__ void cvt_bf16_kernel(const float* __restrict__ x,
                                unsigned short* __restrict__ o, int n4){
  const int stride = gridDim.x * blockDim.x;
  for (int i = blockIdx.x * blockDim.x + threadIdx.x; i < n4; i += stride){
    const float4 v = ((const float4*)x)[i];
    ushort4 u; u.x = f2bf(v.x); u.y = f2bf(v.y); u.z = f2bf(v.z); u.w = f2bf(v.w);
    ((ushort4*)o)[i] = u;
  }
}

// ---------------- gate: softmax + group-limited top-k ----------------
__global__ void gate_kernel(const float* __restrict__ x, const float* __restrict__ Wg,
                            int* __restrict__ cnt, int* __restrict__ list,
                            float* __restrict__ wslot){
  const int t = blockIdx.x;
  const int l = threadIdx.x;
  const int e = l & 15, q = l >> 4;
  const float* xr = x + (size_t)t * D_MODEL + q * 512;
  const float* wr = Wg + (size_t)e * D_MODEL + q * 512;
  float p = 0.f;
  #pragma unroll 4
  for (int i = 0; i < 512; i += 4){
    float4 xv = *(const float4*)(xr + i);
    float4 wv = *(const float4*)(wr + i);
    p += xv.x*wv.x + xv.y*wv.y + xv.z*wv.z + xv.w*wv.w;
  }
  p += __shfl_xor(p, 16);
  p += __shfl_xor(p, 32);
  float mx = p;
  for (int d = 1; d < 16; d <<= 1) mx = fmaxf(mx, __shfl_xor(mx, d));
  float ex = __expf(p - mx);
  float sum = ex;
  for (int d = 1; d < 16; d <<= 1) sum += __shfl_xor(sum, d);
  const float sc = ex / sum;
  float gm = fmaxf(sc, __shfl_xor(sc, 1));
  gm = fmaxf(gm, __shfl_xor(gm, 2));
  const float g0 = __shfl(gm, 0), g1 = __shfl(gm, 4),
              g2 = __shfl(gm, 8), g3 = __shfl(gm, 12);
  const int grp = e >> 2;
  const float gs[4] = {g0, g1, g2, g3};
  int grank = 0;
  #pragma unroll
  for (int j = 0; j < 4; ++j)
    if (gs[j] > gm || (gs[j] == gm && j < grp)) grank++;
  const float msc = (grank < 2) ? sc : -INFINITY;
  int erank = 0;
  #pragma unroll
  for (int j = 0; j < 16; ++j){
    const float oj = __shfl(msc, j);
    if (oj > msc || (oj == msc && j < e)) erank++;
  }
  if (q == 0 && erank < 4 && msc > -INFINITY){
    const int pos = atomicAdd(&cnt[e], 1);
    const int slot = (t << 2) | erank;
    list[e * T_TOK + pos] = slot;
    wslot[slot] = sc;            // ROUTE_SCALE = 1
  }
}

// ==== fused gate+up GEMM with SwiGLU epilogue ====
// BM=128, BN=256 (G-panel 128 | U-panel 128), BK=32, 4 waves (2x2 of 64x128).
// Waves wc=0 compute G, wc=1 compute U for the SAME (row,col) coords; U is
// exchanged through LDS scratch; output H = silu(G)*U bf16, width NI.
// 3-buffer counted-vmcnt pipeline (R6-proven): 6 gloads/tile -> 12/6/0.
template<int GATHER>
__global__ __launch_bounds__(256, 2)
void gemm_gu_kernel(const unsigned short* __restrict__ A,
                    const unsigned short* __restrict__ BG,
                    const unsigned short* __restrict__ BU,
                    unsigned short* __restrict__ H,
                    const int* __restrict__ list,
                    const int* __restrict__ cnt,
                    int ebase, int K, int NI, int MT, int NT)
{
  __shared__ __align__(128) char smem[24576 + 49152];  // As 24K | Bs 48K; epi scratch 64K
  unsigned short* As = (unsigned short*)smem;
  unsigned short* Bs = (unsigned short*)(smem + 24576);
  float* scr = (float*)smem;

  const int per = gridDim.x >> 3;                      // bijective XCD swizzle (grid%8==0)
  const int gsw = (blockIdx.x & 7) * per + (blockIdx.x >> 3);
  const int mt   = gsw % MT;
  const int rest = gsw / MT;
  const int nt = GATHER ? (rest % NT) : rest;
  const int e  = GATHER ? (ebase + rest / NT) : 0;
  const int cntE = GATHER ? cnt[e] : (MT * 128);
  if (mt * 128 >= cntE) return;

  const int tid = threadIdx.x, wid = tid >> 6, lane = tid & 63;
  const int sx = ((lane & 3) ^ ((lane >> 3) & 3)) << 3;   // src 16B-slot XOR, shorts

  // ---- A staging: wave w rows [32w,32w+32), 2 insts x 16 rows ----
  const int rt0 = 32 * wid + (lane >> 2), rt1 = rt0 + 16;
  int ar0, ar1;
  if (GATHER){
    const int lim = cntE - 1;
    int p0 = mt * 128 + rt0; p0 = p0 < lim ? p0 : lim;
    int p1 = mt * 128 + rt1; p1 = p1 < lim ? p1 : lim;
    ar0 = list[e * T_TOK + p0] >> 2;                   // token row
    ar1 = list[e * T_TOK + p1] >> 2;
  } else { ar0 = mt * 128 + rt0; ar1 = mt * 128 + rt1; }
  const unsigned short* pa0 = A + (size_t)ar0 * K + sx;
  const unsigned short* pa1 = A + (size_t)ar1 * K + sx;

  // ---- B staging: wave w rows [64w,64w+64), 4 insts x 16 rows ----
  // waves 0-1 stage the G panel (BG), waves 2-3 the U panel (BU).
  const unsigned short* wsrc = (wid < 2) ? BG : BU;
  if (GATHER) wsrc += (size_t)(e - ebase) * NI * K;
  const int rb = (64 * wid + (lane >> 2)) & 127;       // panel-local row, inst j=0
  const unsigned short* pb0 = wsrc + (size_t)(nt * 128 + rb     ) * K + sx;
  const unsigned short* pb1 = wsrc + (size_t)(nt * 128 + rb + 16) * K + sx;
  const unsigned short* pb2 = wsrc + (size_t)(nt * 128 + rb + 32) * K + sx;
  const unsigned short* pb3 = wsrc + (size_t)(nt * 128 + rb + 48) * K + sx;

  const int aW0 = (32 * wid) * 32, aW1 = aW0 + 512;    // shorts
  const int bW  = (64 * wid) * 32;                     // shorts
  const int aStr = 128 * 32, bStr = 256 * 32;

  const int wr = wid >> 1, wc = wid & 1, lr = lane & 15, lq = lane >> 4;
  const int fx = ((lq ^ ((lr >> 1) & 3)) << 3);
  int aoff[4], boff[8];
  #pragma unroll
  for (int m = 0; m < 4; ++m) aoff[m] = (wr * 64 + m * 16 + lr) * 32 + fx;
  #pragma unroll
  for (int n = 0; n < 8; ++n) boff[n] = (wc * 128 + n * 16 + lr) * 32 + fx;

  f32x4 acc[4][8];
  const f32x4 zero = {0.f, 0.f, 0.f, 0.f};
  #pragma unroll
  for (int m = 0; m < 4; ++m)
    #pragma unroll
    for (int n = 0; n < 8; ++n) acc[m][n] = zero;

  const int KT = K >> 5;
  #pragma unroll
  for (int t = 0; t < 3; ++t){
    GLOAD16(pa0, As + t * aStr + aW0);
    GLOAD16(pa1, As + t * aStr + aW1);
    GLOAD16(pb0, Bs + t * bStr + bW);
    GLOAD16(pb1, Bs + t * bStr + bW + 512);
    GLOAD16(pb2, Bs + t * bStr + bW + 1024);
    GLOAD16(pb3, Bs + t * bStr + bW + 1536);
    pa0 += 32; pa1 += 32; pb0 += 32; pb1 += 32; pb2 += 32; pb3 += 32;
  }
  int c = 0;

  for (int kt = 0; kt < KT; ++kt){
    if (kt < KT - 2)       asm volatile("s_waitcnt vmcnt(12)" ::: "memory");
    else if (kt == KT - 2) asm volatile("s_waitcnt vmcnt(6)"  ::: "memory");
    else                   asm volatile("s_waitcnt vmcnt(0)"  ::: "memory");
    __builtin_amdgcn_s_barrier();            // tile kt visible

    const unsigned short* aC = As + c * aStr;
    const unsigned short* bC = Bs + c * bStr;
    bf16x8 af[4], bf[8];
    #pragma unroll
    for (int m = 0; m < 4; ++m) af[m] = *(const bf16x8*)(aC + aoff[m]);
    #pragma unroll
    for (int n = 0; n < 8; ++n) bf[n] = *(const bf16x8*)(bC + boff[n]);

    asm volatile("s_waitcnt lgkmcnt(0)" ::: "memory");
    __builtin_amdgcn_sched_barrier(0);
    __builtin_amdgcn_s_barrier();            // all waves done reading buf c

    if (kt + 3 < KT){                        // refill buf c with tile kt+3
      GLOAD16(pa0, As + c * aStr + aW0);
      GLOAD16(pa1, As + c * aStr + aW1);
      GLOAD16(pb0, Bs + c * bStr + bW);
      GLOAD16(pb1, Bs + c * bStr + bW + 512);
      GLOAD16(pb2, Bs + c * bStr + bW + 1024);
      GLOAD16(pb3, Bs + c * bStr + bW + 1536);
      pa0 += 32; pa1 += 32; pb0 += 32; pb1 += 32; pb2 += 32; pb3 += 32;
    }

    #pragma unroll
    for (int n = 0; n < 8; ++n)
      #pragma unroll
      for (int m = 0; m < 4; ++m)
        acc[m][n] = __builtin_amdgcn_mfma_f32_16x16x32_bf16(af[m], bf[n], acc[m][n], 0, 0, 0);

    c = (c == 2) ? 0 : c + 1;
  }

  // ---- SwiGLU epilogue: U-waves (wc=1) park acc in LDS; G-waves combine ----
  // C/D layout: col = lane&15, row = (lane>>4)*4 + reg  [m89/m91]
  if (wc == 1){
    #pragma unroll
    for (int m = 0; m < 4; ++m)
      #pragma unroll
      for (int r = 0; r < 4; ++r){
        const int row = m * 16 + lq * 4 + r;
        #pragma unroll
        for (int n = 0; n < 8; ++n){
          const int ucol = (n * 16 + lr) ^ ((lq & 1) << 4);  // 2-way banks
          scr[wr * 8192 + row * 128 + ucol] = acc[m][n][r];
        }
      }
  }
  __syncthreads();
  if (wc == 0){
    #pragma unroll
    for (int m = 0; m < 4; ++m)
      #pragma unroll
      for (int r = 0; r < 4; ++r){
        const int row = m * 16 + lq * 4 + r;
        const int grow = mt * 128 + wr * 64 + row;
        if (GATHER && grow >= cntE) continue;
        const int orow = GATHER ? list[e * T_TOK + grow] : grow;   // slot / token
        unsigned short* op = H + (size_t)orow * NI + nt * 128;
        #pragma unroll
        for (int n = 0; n < 8; ++n){
          const float g = acc[m][n][r];
          const int ucol = (n * 16 + lr) ^ ((lq & 1) << 4);
          const float u = scr[wr * 8192 + row * 128 + ucol];
          op[n * 16 + lr] = f2bf(g / (1.f + __expf(-g)) * u);
        }
      }
  }
}

// ==== down-projection GEMM: BM=128, BN=256, single B ====
// GATHER=0: linear A (Hs), fp32 plain store to out (initializes d_out)
// GATHER=1: A gathered by slot (Hr), bf16 store to H2[slot]
template<int GATHER>
__global__ __launch_bounds__(256, 2)
void gemm_down_kernel(const unsigned short* __restrict__ A,
                      const unsigned short* __restrict__ B,
                      void* __restrict__ OutP,
                      const int* __restrict__ list,
                      const int* __restrict__ cnt,
                      int K, int N, int MT, int NT)
{
  __shared__ __align__(128) char smem[24576 + 49152];
  unsigned short* As = (unsigned short*)smem;
  unsigned short* Bs = (unsigned short*)(smem + 24576);

  const int per = gridDim.x >> 3;
  const int gsw = (blockIdx.x & 7) * per + (blockIdx.x >> 3);
  const int mt   = gsw % MT;
  const int rest = gsw / MT;
  const int nt = GATHER ? (rest % NT) : rest;
  const int e  = GATHER ? (rest / NT) : 0;
  const int cntE = GATHER ? cnt[e] : (MT * 128);
  if (mt * 128 >= cntE) return;

  const int tid = threadIdx.x, wid = tid >> 6, lane = tid & 63;
  const int sx = ((lane & 3) ^ ((lane >> 3) & 3)) << 3;

  const int rt0 = 32 * wid + (lane >> 2), rt1 = rt0 + 16;
  int ar0, ar1;
  if (GATHER){
    const int lim = cntE - 1;
    int p0 = mt * 128 + rt0; p0 = p0 < lim ? p0 : lim;
    int p1 = mt * 128 + rt1; p1 = p1 < lim ? p1 : lim;
    ar0 = list[e * T_TOK + p0];                        // slot row
    ar1 = list[e * T_TOK + p1];
  } else { ar0 = mt * 128 + rt0; ar1 = mt * 128 + rt1; }
  const unsigned short* pa0 = A + (size_t)ar0 * K + sx;
  const unsigned short* pa1 = A + (size_t)ar1 * K + sx;

  const unsigned short* wsrc = B + (GATHER ? (size_t)e * N * K : 0);
  const int rb = 64 * wid + (lane >> 2);               // B tile row, inst j=0
  const unsigned short* pb0 = wsrc + (size_t)(nt * 256 + rb     ) * K + sx;
  const unsigned short* pb1 = wsrc + (size_t)(nt * 256 + rb + 16) * K + sx;
  const unsigned short* pb2 = wsrc + (size_t)(nt * 256 + rb + 32) * K + sx;
  const unsigned short* pb3 = wsrc + (size_t)(nt * 256 + rb + 48) * K + sx;

  const int aW0 = (32 * wid) * 32, aW1 = aW0 + 512;
  const int bW  = (64 * wid) * 32;
  const int aStr = 128 * 32, bStr = 256 * 32;

  const int wr = wid >> 1, wc = wid & 1, lr = lane & 15, lq = lane >> 4;
  const int fx = ((lq ^ ((lr >> 1) & 3)) << 3);
  int aoff[4], boff[8];
  #pragma unroll
  for (int m = 0; m < 4; ++m) aoff[m] = (wr * 64 + m * 16 + lr) * 32 + fx;
  #pragma unroll
  for (int n = 0; n < 8; ++n) boff[n] = (wc * 128 + n * 16 + lr) * 32 + fx;

  f32x4 acc[4][8];
  const f32x4 zero = {0.f, 0.f, 0.f, 0.f};
  #pragma unroll
  for (int m = 0; m < 4; ++m)
    #pragma unroll
    for (int n = 0; n < 8; ++n) acc[m][n] = zero;

  const int KT = K >> 5;
  #pragma unroll
  for (int t = 0; t < 3; ++t){
    GLOAD16(pa0, As + t * aStr + aW0);
    GLOAD16(pa1, As + t * aStr + aW1);
    GLOAD16(pb0, Bs + t * bStr + bW);
    GLOAD16(pb1, Bs + t * bStr + bW + 512);
    GLOAD16(pb2, Bs + t * bStr + bW + 1024);
    GLOAD16(pb3, Bs + t * bStr + bW + 1536);
    pa0 += 32; pa1 += 32; pb0 += 32; pb1 += 32; pb2 += 32; pb3 += 32;
  }
  int c = 0;

  for (int kt = 0; kt < KT; ++kt){
    if (kt < KT - 2)       asm volatile("s_waitcnt vmcnt(12)" ::: "memory");
    else if (kt == KT - 2) asm volatile("s_waitcnt vmcnt(6)"  ::: "memory");
    else                   asm volatile("s_waitcnt vmcnt(0)"  ::: "memory");
    __builtin_amdgcn_s_barrier();

    const unsigned short* aC = As + c * aStr;
    const unsigned short* bC = Bs + c * bStr;
    bf16x8 af[4], bf[8];
    #pragma unroll
    for (int m = 0; m < 4; ++m) af[m] = *(const bf16x8*)(aC + aoff[m]);
    #pragma unroll
    for (int n = 0; n < 8; ++n) bf[n] = *(const bf16x8*)(bC + boff[n]);

    asm volatile("s_waitcnt lgkmcnt(0)" ::: "memory");
    __builtin_amdgcn_sched_barrier(0);
    __builtin_amdgcn_s_barrier();

    if (kt + 3 < KT){
      GLOAD16(pa0, As + c * aStr + aW0);
      GLOAD16(pa1, As + c * aStr + aW1);
      GLOAD16(pb0, Bs + c * bStr + bW);
      GLOAD16(pb1, Bs + c * bStr + bW + 512);
      GLOAD16(pb2, Bs + c * bStr + bW + 1024);
      GLOAD16(pb3, Bs + c * bStr + bW + 1536);
      pa0 += 32; pa1 += 32; pb0 += 32; pb1 += 32; pb2 += 32; pb3 += 32;
    }

    #pragma unroll
    for (int n = 0; n < 8; ++n)
      #pragma unroll
      for (int m = 0; m < 4; ++m)
        acc[m][n] = __builtin_amdgcn_mfma_f32_16x16x32_bf16(af[m], bf[n], acc[m][n], 0, 0, 0);

    c = (c == 2) ? 0 : c + 1;
  }

  const int colBase = nt * 256 + wc * 128;
  #pragma unroll
  for (int m = 0; m < 4; ++m){
    #pragma unroll
    for (int r = 0; r < 4; ++r){
      const int grow = mt * 128 + wr * 64 + m * 16 + lq * 4 + r;
      if (GATHER == 0){
        float* op = (float*)OutP + (size_t)grow * N + colBase;
        #pragma unroll
        for (int n = 0; n < 8; ++n) op[n * 16 + lr] = acc[m][n][r];
      } else {
        if (grow >= cntE) continue;
        const int orow = list[e * T_TOK + grow];       // slot
        unsigned short* op = (unsigned short*)OutP + (size_t)orow * N + colBase;
        #pragma unroll
        for (int n = 0; n < 8; ++n) op[n * 16 + lr] = f2bf(acc[m][n][r]);
      }
    }
  }
}

// ---- combine: out[t] += sum_k wslot[4t+k] * H2[4t+k] ----
__global__ void combine_kernel(const unsigned short* __restrict__ H2,
                               const float* __restrict__ wslot,
                               float* __restrict__ out){
  const int t = blockIdx.x;
  const int ccol = threadIdx.x * 8;
  float w[4];
  #pragma unroll
  for (int k = 0; k < 4; ++k) w[k] = wslot[t * 4 + k];
  float* o = out + (size_t)t * D_MODEL + ccol;
  float a[8];
  #pragma unroll
  for (int j = 0; j < 8; ++j) a[j] = o[j];
  #pragma unroll
  for (int k = 0; k < 4; ++k){
    const bf16x8 hv = *(const bf16x8*)(H2 + (size_t)(t * 4 + k) * D_MODEL + ccol);
    #pragma unroll
    for (int j = 0; j < 8; ++j) a[j] += w[k] * bf2f((unsigned short)hv[j]);
  }
  #pragma unroll
  for (int j = 0; j < 8; ++j) o[j] = a[j];
}

extern "C" void kernel_launch(void* const* d_in, const int* in_sizes, int n_in,
                              void* d_out, int out_size, void* d_ws, size_t ws_size,
                              hipStream_t stream)
{
  const float* x   = (const float*)d_in[0];
  const float* Wg  = (const float*)d_in[1];
  const float* W1  = (const float*)d_in[2];
  const float* W3  = (const float*)d_in[3];
  const float* W2  = (const float*)d_in[4];
  const float* Ws1 = (const float*)d_in[5];
  const float* Ws3 = (const float*)d_in[6];
  const float* Ws2 = (const float*)d_in[7];
  float* out = (float*)d_out;

  // ---- phase-reused workspace, max touched 145 MiB (R5 proved 150.6 safe) ----
  char* ws = (char*)d_ws;
  int*   cnt   = (int*)(ws);                     // 64 B
  int*   list  = (int*)(ws + 4096);              // 128 KiB
  float* wslot = (float*)(ws + 4096 + 131072);   // 32 KiB
  unsigned short* xbf = (unsigned short*)(ws + MIB(1));   // 8 MiB  [dead before H2]
  unsigned short* H2  = (unsigned short*)(ws + MIB(1));   // 32 MiB [routed-down out]
  unsigned short* Hs  = (unsigned short*)(ws + MIB(10));  // 11 MiB [dead before H2]
  unsigned short* Hr  = (unsigned short*)(ws + MIB(34));  // 22 MiB [routed H]
  unsigned short* WA  = (unsigned short*)(ws + MIB(57));  // weight window lo (44/88 MiB)
  unsigned short* WB  = (unsigned short*)(ws + MIB(101)); // weight window hi (44 MiB)

  hipMemsetAsync(cnt, 0, 4096, stream);
  cvt_bf16_kernel<<<2048, 256, 0, stream>>>(x, xbf, T_TOK * D_MODEL / 4);
  gate_kernel<<<T_TOK, 64, 0, stream>>>(x, Wg, cnt, list, wslot);

  // ---- shared expert ----
  cvt_bf16_kernel<<<2048, 256, 0, stream>>>(Ws1, WA, SH_INTER * D_MODEL / 4);
  cvt_bf16_kernel<<<2048, 256, 0, stream>>>(Ws3, WB, SH_INTER * D_MODEL / 4);
  // fused G+U+SwiGLU -> Hs : grid 16x22 = 352
  gemm_gu_kernel<0><<<16 * 22, 256, 0, stream>>>(xbf, WA, WB, Hs, nullptr, nullptr,
                                                 0, D_MODEL, SH_INTER, 16, 22);
  cvt_bf16_kernel<<<2048, 256, 0, stream>>>(Ws2, WA, D_MODEL * SH_INTER / 4);
  // shared down -> out (plain fp32 stores initialize d_out): grid 16x8 = 128
  gemm_down_kernel<0><<<16 * 8, 256, 0, stream>>>(Hs, WA, out, nullptr, nullptr,
                                                  SH_INTER, D_MODEL, 16, 8);

  // ---- routed experts: two 8-expert halves (weight window 88 MiB) ----
  for (int h = 0; h < 2; ++h){
    const size_t wOff = (size_t)(8 * h) * N_INTER * D_MODEL;
    cvt_bf16_kernel<<<4096, 256, 0, stream>>>(W1 + wOff, WA, (int)(8u * N_INTER * D_MODEL / 4));
    cvt_bf16_kernel<<<4096, 256, 0, stream>>>(W3 + wOff, WB, (int)(8u * N_INTER * D_MODEL / 4));
    // fused G+U+SwiGLU -> Hr[slot] : grid 16x11x8 = 1408
    gemm_gu_kernel<1><<<16 * 11 * 8, 256, 0, stream>>>(xbf, WA, WB, Hr, list, cnt,
                                                       8 * h, D_MODEL, N_INTER, 16, 11);
  }
  // cvt all 16 experts of W2 into the 88 MiB window
  cvt_bf16_kernel<<<8192, 256, 0, stream>>>(W2, WA, 16 * D_MODEL * N_INTER / 4);
  // routed down -> H2[slot] : grid 16x8x16 = 2048
  gemm_down_kernel<1><<<16 * 8 * 16, 256, 0, stream>>>(Hr, WA, H2, list, cnt,
                                                       N_INTER, D_MODEL, 16, 8);
  combine_kernel<<<T_TOK, 256, 0, stream>>>(H2, wslot, out);
}

// Round 8
// 613.074 us; speedup vs baseline: 1.0445x; 1.0445x over previous
//
#include <hip/hip_runtime.h>
#include <stdint.h>

// ---- problem constants ----
#define D_MODEL  2048
#define N_INTER  1408
#define SH_INTER 2816
#define T_TOK    2048
#define NSLOT    (T_TOK * 4)
#define MIB(x)   ((size_t)(x) << 20)

typedef __attribute__((ext_vector_type(8))) short bf16x8;
typedef __attribute__((ext_vector_type(4))) float f32x4;

__device__ __forceinline__ unsigned short f2bf(float f){
  unsigned int b = __builtin_bit_cast(unsigned int, f);
  b = (b + 0x7FFFu + ((b >> 16) & 1u)) >> 16;   // RNE, finite inputs
  return (unsigned short)b;
}
__device__ __forceinline__ float bf2f(unsigned short h){
  unsigned int b = ((unsigned int)h) << 16;
  return __builtin_bit_cast(float, b);
}

// async global->LDS, 16B per lane; LDS dest = wave-uniform base + lane*16
#define GLOAD16(gp, lp) __builtin_amdgcn_global_load_lds( \
    (const __attribute__((address_space(1))) unsigned int*)(gp), \
    (__attribute__((address_space(3))) unsigned int*)(lp), 16, 0, 0)

// ---------------- fp32 -> bf16 streaming convert ----------------
__global__ void cvt_bf16_kernel(const float* __restrict__ x,
                                unsigned short* __restrict__ o, int n4){
  const int stride = gridDim.x * blockDim.x;
  for (int i = blockIdx.x * blockDim.x + threadIdx.x; i < n4; i += stride){
    const float4 v = ((const float4*)x)[i];
    ushort4 u; u.x = f2bf(v.x); u.y = f2bf(v.y); u.z = f2bf(v.z); u.w = f2bf(v.w);
    ((ushort4*)o)[i] = u;
  }
}

// ---------------- gate: softmax + group-limited top-k ----------------
__global__ void gate_kernel(const float* __restrict__ x, const float* __restrict__ Wg,
                            int* __restrict__ cnt, int* __restrict__ list,
                            float* __restrict__ wslot){
  const int t = blockIdx.x;
  const int l = threadIdx.x;
  const int e = l & 15, q = l >> 4;
  const float* xr = x + (size_t)t * D_MODEL + q * 512;
  const float* wr = Wg + (size_t)e * D_MODEL + q * 512;
  float p = 0.f;
  #pragma unroll 4
  for (int i = 0; i < 512; i += 4){
    float4 xv = *(const float4*)(xr + i);
    float4 wv = *(const float4*)(wr + i);
    p += xv.x*wv.x + xv.y*wv.y + xv.z*wv.z + xv.w*wv.w;
  }
  p += __shfl_xor(p, 16);
  p += __shfl_xor(p, 32);
  float mx = p;
  for (int d = 1; d < 16; d <<= 1) mx = fmaxf(mx, __shfl_xor(mx, d));
  float ex = __expf(p - mx);
  float sum = ex;
  for (int d = 1; d < 16; d <<= 1) sum += __shfl_xor(sum, d);
  const float sc = ex / sum;
  float gm = fmaxf(sc, __shfl_xor(sc, 1));
  gm = fmaxf(gm, __shfl_xor(gm, 2));
  const float g0 = __shfl(gm, 0), g1 = __shfl(gm, 4),
              g2 = __shfl(gm, 8), g3 = __shfl(gm, 12);
  const int grp = e >> 2;
  const float gs[4] = {g0, g1, g2, g3};
  int grank = 0;
  #pragma unroll
  for (int j = 0; j < 4; ++j)
    if (gs[j] > gm || (gs[j] == gm && j < grp)) grank++;
  const float msc = (grank < 2) ? sc : -INFINITY;
  int erank = 0;
  #pragma unroll
  for (int j = 0; j < 16; ++j){
    const float oj = __shfl(msc, j);
    if (oj > msc || (oj == msc && j < e)) erank++;
  }
  if (q == 0 && erank < 4 && msc > -INFINITY){
    const int pos = atomicAdd(&cnt[e], 1);
    const int slot = (t << 2) | erank;
    list[e * T_TOK + pos] = slot;
    wslot[slot] = sc;            // ROUTE_SCALE = 1
  }
}

// ==== fused dual-B gate+up GEMM, BM=128 BN=128 BK=32, 4 waves (2x2 of 64x64) ====
// Every wave computes BOTH G and U accumulators for its 64x64 coords; SwiGLU is
// applied in-register in the epilogue (no LDS exchange, no swiglu pass).
// 3-buffer counted-vmcnt pipeline, 6 gloads/tile -> vmcnt 12/6/0.
// GATHER=0: linear A rows, H[row][NI].  GATHER=1: A by token (list>>2), H[slot][NI].
template<int GATHER>
__global__ __launch_bounds__(256, 2)
void gemm_gu2_kernel(const unsigned short* __restrict__ A,
                     const unsigned short* __restrict__ BG,
                     const unsigned short* __restrict__ BU,
                     unsigned short* __restrict__ H,
                     const int* __restrict__ list,
                     const int* __restrict__ cnt,
                     int K, int NI, int MT, int NT)
{
  __shared__ unsigned short As [3 * 4096];   // 24 KB
  __shared__ unsigned short BsG[3 * 4096];   // 24 KB
  __shared__ unsigned short BsU[3 * 4096];   // 24 KB

  const int per = gridDim.x >> 3;            // bijective XCD swizzle (grid%8==0)
  const int gsw = (blockIdx.x & 7) * per + (blockIdx.x >> 3);
  const int mt   = gsw % MT;
  const int rest = gsw / MT;
  const int nt = GATHER ? (rest % NT) : rest;
  const int e  = GATHER ? (rest / NT) : 0;
  const int cntE = GATHER ? cnt[e] : (MT * 128);
  if (mt * 128 >= cntE) return;

  const int tid = threadIdx.x, wid = tid >> 6, lane = tid & 63;
  const int sx = ((lane & 3) ^ ((lane >> 3) & 3)) << 3;   // src 16B-slot XOR, shorts

  // ---- staging rows: wave w covers rows [32w,32w+32), 2 insts x 16 rows ----
  const int rt0 = 32 * wid + (lane >> 2), rt1 = rt0 + 16;
  int ar0, ar1;
  if (GATHER){
    const int lim = cntE - 1;
    int p0 = mt * 128 + rt0; p0 = p0 < lim ? p0 : lim;
    int p1 = mt * 128 + rt1; p1 = p1 < lim ? p1 : lim;
    ar0 = list[e * T_TOK + p0] >> 2;                      // token row
    ar1 = list[e * T_TOK + p1] >> 2;
  } else { ar0 = mt * 128 + rt0; ar1 = mt * 128 + rt1; }
  const unsigned short* pa0 = A + (size_t)ar0 * K + sx;
  const unsigned short* pa1 = A + (size_t)ar1 * K + sx;

  const size_t eoff = GATHER ? (size_t)e * NI * K : 0;
  const unsigned short* pg0 = BG + eoff + (size_t)(nt * 128 + rt0) * K + sx;
  const unsigned short* pg1 = pg0 + (size_t)16 * K;
  const unsigned short* pu0 = BU + eoff + (size_t)(nt * 128 + rt0) * K + sx;
  const unsigned short* pu1 = pu0 + (size_t)16 * K;

  const int w0 = (32 * wid) * 32, w1 = w0 + 512;          // shorts
  const int bufStr = 4096;

  // fragment read offsets (XOR-swizzled)
  const int wr = wid >> 1, wc = wid & 1, lr = lane & 15, lq = lane >> 4;
  const int fx = ((lq ^ ((lr >> 1) & 3)) << 3);
  int aoff[4], boff[4];
  #pragma unroll
  for (int m = 0; m < 4; ++m) aoff[m] = (wr * 64 + m * 16 + lr) * 32 + fx;
  #pragma unroll
  for (int n = 0; n < 4; ++n) boff[n] = (wc * 64 + n * 16 + lr) * 32 + fx;

  f32x4 accg[4][4], accu[4][4];
  const f32x4 zero = {0.f, 0.f, 0.f, 0.f};
  #pragma unroll
  for (int m = 0; m < 4; ++m)
    #pragma unroll
    for (int n = 0; n < 4; ++n){ accg[m][n] = zero; accu[m][n] = zero; }

  const int KT = K >> 5;
  #pragma unroll
  for (int t = 0; t < 3; ++t){
    GLOAD16(pa0, As  + t * bufStr + w0);
    GLOAD16(pa1, As  + t * bufStr + w1);
    GLOAD16(pg0, BsG + t * bufStr + w0);
    GLOAD16(pg1, BsG + t * bufStr + w1);
    GLOAD16(pu0, BsU + t * bufStr + w0);
    GLOAD16(pu1, BsU + t * bufStr + w1);
    pa0 += 32; pa1 += 32; pg0 += 32; pg1 += 32; pu0 += 32; pu1 += 32;
  }
  int c = 0;

  for (int kt = 0; kt < KT; ++kt){
    if (kt < KT - 2)       asm volatile("s_waitcnt vmcnt(12)" ::: "memory");
    else if (kt == KT - 2) asm volatile("s_waitcnt vmcnt(6)"  ::: "memory");
    else                   asm volatile("s_waitcnt vmcnt(0)"  ::: "memory");
    __builtin_amdgcn_s_barrier();            // tile kt visible

    const unsigned short* aC = As  + c * bufStr;
    const unsigned short* gC = BsG + c * bufStr;
    const unsigned short* uC = BsU + c * bufStr;
    bf16x8 af[4], bg[4], bu[4];
    #pragma unroll
    for (int m = 0; m < 4; ++m) af[m] = *(const bf16x8*)(aC + aoff[m]);
    #pragma unroll
    for (int n = 0; n < 4; ++n) bg[n] = *(const bf16x8*)(gC + boff[n]);
    #pragma unroll
    for (int n = 0; n < 4; ++n) bu[n] = *(const bf16x8*)(uC + boff[n]);

    asm volatile("s_waitcnt lgkmcnt(0)" ::: "memory");
    __builtin_amdgcn_sched_barrier(0);
    __builtin_amdgcn_s_barrier();            // all waves done reading buf c

    if (kt + 3 < KT){                        // refill buf c with tile kt+3
      GLOAD16(pa0, As  + c * bufStr + w0);
      GLOAD16(pa1, As  + c * bufStr + w1);
      GLOAD16(pg0, BsG + c * bufStr + w0);
      GLOAD16(pg1, BsG + c * bufStr + w1);
      GLOAD16(pu0, BsU + c * bufStr + w0);
      GLOAD16(pu1, BsU + c * bufStr + w1);
      pa0 += 32; pa1 += 32; pg0 += 32; pg1 += 32; pu0 += 32; pu1 += 32;
    }

    __builtin_amdgcn_s_setprio(1);
    #pragma unroll
    for (int n = 0; n < 4; ++n)
      #pragma unroll
      for (int m = 0; m < 4; ++m){
        accg[m][n] = __builtin_amdgcn_mfma_f32_16x16x32_bf16(af[m], bg[n], accg[m][n], 0, 0, 0);
        accu[m][n] = __builtin_amdgcn_mfma_f32_16x16x32_bf16(af[m], bu[n], accu[m][n], 0, 0, 0);
      }
    __builtin_amdgcn_s_setprio(0);

    c = (c == 2) ? 0 : c + 1;
  }

  // ---- epilogue: H = silu(G)*U ; C/D col = lane&15, row = (lane>>4)*4 + reg ----
  const int colBase = nt * 128 + wc * 64;
  #pragma unroll
  for (int m = 0; m < 4; ++m){
    #pragma unroll
    for (int r = 0; r < 4; ++r){
      const int grow = mt * 128 + wr * 64 + m * 16 + lq * 4 + r;
      if (GATHER && grow >= cntE) continue;
      const int orow = GATHER ? list[e * T_TOK + grow] : grow;   // slot / row
      unsigned short* op = H + (size_t)orow * NI + colBase;
      #pragma unroll
      for (int n = 0; n < 4; ++n){
        const float g = accg[m][n][r], u = accu[m][n][r];
        op[n * 16 + lr] = f2bf(g / (1.f + __expf(-g)) * u);
      }
    }
  }
}

// ==== down-projection GEMM: BM=128, BN=256, single B, optional K-split ====
// GATHER=0: linear A, fp32 partial store to OutP + ks*M*N (K-split KS)
// GATHER=1: A gathered by slot, bf16 store to H2[slot] (KS must be 1)
template<int GATHER, int KS>
__global__ __launch_bounds__(256, 2)
void gemm_down_kernel(const unsigned short* __restrict__ A,
                      const unsigned short* __restrict__ B,
                      void* __restrict__ OutP,
                      const int* __restrict__ list,
                      const int* __restrict__ cnt,
                      int K, int N, int MT, int NT)
{
  __shared__ __align__(128) char smem[24576 + 49152];   // As 24K | Bs 48K
  unsigned short* As = (unsigned short*)smem;
  unsigned short* Bs = (unsigned short*)(smem + 24576);

  const int per = gridDim.x >> 3;
  const int gsw = (blockIdx.x & 7) * per + (blockIdx.x >> 3);
  const int mt   = gsw % MT;
  int rest = gsw / MT;
  const int nt = rest % NT; rest /= NT;
  const int ks = (KS > 1) ? (rest % KS) : 0;
  const int e  = GATHER ? (rest / (KS > 1 ? KS : 1)) : 0;
  const int cntE = GATHER ? cnt[e] : (MT * 128);
  if (mt * 128 >= cntE) return;

  const int tid = threadIdx.x, wid = tid >> 6, lane = tid & 63;
  const int sx = ((lane & 3) ^ ((lane >> 3) & 3)) << 3;
  const int kOff = ks * (K / KS);

  const int rt0 = 32 * wid + (lane >> 2), rt1 = rt0 + 16;
  int ar0, ar1;
  if (GATHER){
    const int lim = cntE - 1;
    int p0 = mt * 128 + rt0; p0 = p0 < lim ? p0 : lim;
    int p1 = mt * 128 + rt1; p1 = p1 < lim ? p1 : lim;
    ar0 = list[e * T_TOK + p0];                        // slot row
    ar1 = list[e * T_TOK + p1];
  } else { ar0 = mt * 128 + rt0; ar1 = mt * 128 + rt1; }
  const unsigned short* pa0 = A + (size_t)ar0 * K + kOff + sx;
  const unsigned short* pa1 = A + (size_t)ar1 * K + kOff + sx;

  const unsigned short* wsrc = B + (GATHER ? (size_t)e * N * K : 0) + kOff;
  const int rb = 64 * wid + (lane >> 2);               // B tile row, inst j=0
  const unsigned short* pb0 = wsrc + (size_t)(nt * 256 + rb     ) * K + sx;
  const unsigned short* pb1 = wsrc + (size_t)(nt * 256 + rb + 16) * K + sx;
  const unsigned short* pb2 = wsrc + (size_t)(nt * 256 + rb + 32) * K + sx;
  const unsigned short* pb3 = wsrc + (size_t)(nt * 256 + rb + 48) * K + sx;

  const int aW0 = (32 * wid) * 32, aW1 = aW0 + 512;
  const int bW  = (64 * wid) * 32;
  const int aStr = 128 * 32, bStr = 256 * 32;

  const int wr = wid >> 1, wc = wid & 1, lr = lane & 15, lq = lane >> 4;
  const int fx = ((lq ^ ((lr >> 1) & 3)) << 3);
  int aoff[4], boff[8];
  #pragma unroll
  for (int m = 0; m < 4; ++m) aoff[m] = (wr * 64 + m * 16 + lr) * 32 + fx;
  #pragma unroll
  for (int n = 0; n < 8; ++n) boff[n] = (wc * 128 + n * 16 + lr) * 32 + fx;

  f32x4 acc[4][8];
  const f32x4 zero = {0.f, 0.f, 0.f, 0.f};
  #pragma unroll
  for (int m = 0; m < 4; ++m)
    #pragma unroll
    for (int n = 0; n < 8; ++n) acc[m][n] = zero;

  const int KT = (K / KS) >> 5;
  #pragma unroll
  for (int t = 0; t < 3; ++t){
    GLOAD16(pa0, As + t * aStr + aW0);
    GLOAD16(pa1, As + t * aStr + aW1);
    GLOAD16(pb0, Bs + t * bStr + bW);
    GLOAD16(pb1, Bs + t * bStr + bW + 512);
    GLOAD16(pb2, Bs + t * bStr + bW + 1024);
    GLOAD16(pb3, Bs + t * bStr + bW + 1536);
    pa0 += 32; pa1 += 32; pb0 += 32; pb1 += 32; pb2 += 32; pb3 += 32;
  }
  int c = 0;

  for (int kt = 0; kt < KT; ++kt){
    if (kt < KT - 2)       asm volatile("s_waitcnt vmcnt(12)" ::: "memory");
    else if (kt == KT - 2) asm volatile("s_waitcnt vmcnt(6)"  ::: "memory");
    else                   asm volatile("s_waitcnt vmcnt(0)"  ::: "memory");
    __builtin_amdgcn_s_barrier();

    const unsigned short* aC = As + c * aStr;
    const unsigned short* bC = Bs + c * bStr;
    bf16x8 af[4], bf[8];
    #pragma unroll
    for (int m = 0; m < 4; ++m) af[m] = *(const bf16x8*)(aC + aoff[m]);
    #pragma unroll
    for (int n = 0; n < 8; ++n) bf[n] = *(const bf16x8*)(bC + boff[n]);

    asm volatile("s_waitcnt lgkmcnt(0)" ::: "memory");
    __builtin_amdgcn_sched_barrier(0);
    __builtin_amdgcn_s_barrier();

    if (kt + 3 < KT){
      GLOAD16(pa0, As + c * aStr + aW0);
      GLOAD16(pa1, As + c * aStr + aW1);
      GLOAD16(pb0, Bs + c * bStr + bW);
      GLOAD16(pb1, Bs + c * bStr + bW + 512);
      GLOAD16(pb2, Bs + c * bStr + bW + 1024);
      GLOAD16(pb3, Bs + c * bStr + bW + 1536);
      pa0 += 32; pa1 += 32; pb0 += 32; pb1 += 32; pb2 += 32; pb3 += 32;
    }

    __builtin_amdgcn_s_setprio(1);
    #pragma unroll
    for (int n = 0; n < 8; ++n)
      #pragma unroll
      for (int m = 0; m < 4; ++m)
        acc[m][n] = __builtin_amdgcn_mfma_f32_16x16x32_bf16(af[m], bf[n], acc[m][n], 0, 0, 0);
    __builtin_amdgcn_s_setprio(0);

    c = (c == 2) ? 0 : c + 1;
  }

  const int colBase = nt * 256 + wc * 128;
  #pragma unroll
  for (int m = 0; m < 4; ++m){
    #pragma unroll
    for (int r = 0; r < 4; ++r){
      const int grow = mt * 128 + wr * 64 + m * 16 + lq * 4 + r;
      if (GATHER == 0){
        float* op = (float*)OutP + (size_t)ks * MT * 128 * N + (size_t)grow * N + colBase;
        #pragma unroll
        for (int n = 0; n < 8; ++n) op[n * 16 + lr] = acc[m][n][r];
      } else {
        if (grow >= cntE) continue;
        const int orow = list[e * T_TOK + grow];       // slot
        unsigned short* op = (unsigned short*)OutP + (size_t)orow * N + colBase;
        #pragma unroll
        for (int n = 0; n < 8; ++n) op[n * 16 + lr] = f2bf(acc[m][n][r]);
      }
    }
  }
}

// ---- combine: out[t] = sum_p P[p][t] + sum_k wslot[4t+k] * H2[4t+k] ----
__global__ void combine_kernel(const unsigned short* __restrict__ H2,
                               const float* __restrict__ P,
                               const float* __restrict__ wslot,
                               float* __restrict__ out){
  const int t = blockIdx.x;
  const int ccol = threadIdx.x * 8;
  float w[4];
  #pragma unroll
  for (int k = 0; k < 4; ++k) w[k] = wslot[t * 4 + k];
  float a[8];
  #pragma unroll
  for (int j = 0; j < 8; ++j) a[j] = 0.f;
  #pragma unroll
  for (int p = 0; p < 4; ++p){
    const float* pp = P + (size_t)(p * T_TOK + t) * D_MODEL + ccol;
    #pragma unroll
    for (int j = 0; j < 8; ++j) a[j] += pp[j];
  }
  #pragma unroll
  for (int k = 0; k < 4; ++k){
    const bf16x8 hv = *(const bf16x8*)(H2 + (size_t)(t * 4 + k) * D_MODEL + ccol);
    #pragma unroll
    for (int j = 0; j < 8; ++j) a[j] += w[k] * bf2f((unsigned short)hv[j]);
  }
  float* o = out + (size_t)t * D_MODEL + ccol;
  #pragma unroll
  for (int j = 0; j < 8; ++j) o[j] = a[j];
}

extern "C" void kernel_launch(void* const* d_in, const int* in_sizes, int n_in,
                              void* d_out, int out_size, void* d_ws, size_t ws_size,
                              hipStream_t stream)
{
  const float* x   = (const float*)d_in[0];
  const float* Wg  = (const float*)d_in[1];
  const float* W1  = (const float*)d_in[2];
  const float* W3  = (const float*)d_in[3];
  const float* W2  = (const float*)d_in[4];
  const float* Ws1 = (const float*)d_in[5];
  const float* Ws3 = (const float*)d_in[6];
  const float* Ws2 = (const float*)d_in[7];
  float* out = (float*)d_out;

  // ---- workspace (ws ~738 MB per harness poison fill; we use ~300 MiB) ----
  char* ws = (char*)d_ws;
  int*   cnt   = (int*)(ws);                     // 64 B
  int*   list  = (int*)(ws + 4096);              // 128 KiB
  float* wslot = (float*)(ws + 4096 + 131072);   // 32 KiB
  unsigned short* xbf = (unsigned short*)(ws + MIB(1));    // 8 MiB  [dead before H2]
  unsigned short* H2  = (unsigned short*)(ws + MIB(1));    // 32 MiB [routed-down out]
  unsigned short* Hs  = (unsigned short*)(ws + MIB(34));   // 11.5 MiB
  unsigned short* Hr  = (unsigned short*)(ws + MIB(46));   // 23 MiB
  float*          P   = (float*)        (ws + MIB(70));    // 67 MiB (4 K-split partials)
  unsigned short* WA  = (unsigned short*)(ws + MIB(138));  // 92 MiB (gate/down weights)
  unsigned short* WB  = (unsigned short*)(ws + MIB(231));  // 92 MiB (up weights)

  hipMemsetAsync(cnt, 0, 4096, stream);
  cvt_bf16_kernel<<<2048, 256, 0, stream>>>(x, xbf, T_TOK * D_MODEL / 4);
  gate_kernel<<<T_TOK, 64, 0, stream>>>(x, Wg, cnt, list, wslot);

  // ---- shared expert ----
  cvt_bf16_kernel<<<2048, 256, 0, stream>>>(Ws1, WA, SH_INTER * D_MODEL / 4);
  cvt_bf16_kernel<<<2048, 256, 0, stream>>>(Ws3, WB, SH_INTER * D_MODEL / 4);
  // fused G+U+SwiGLU -> Hs : grid 16x22 = 352
  gemm_gu2_kernel<0><<<16 * 22, 256, 0, stream>>>(xbf, WA, WB, Hs, nullptr, nullptr,
                                                  D_MODEL, SH_INTER, 16, 22);
  cvt_bf16_kernel<<<2048, 256, 0, stream>>>(Ws2, WA, D_MODEL * SH_INTER / 4);
  // shared down, K-split x4 -> fp32 partials P : grid 16x8x4 = 512
  gemm_down_kernel<0, 4><<<16 * 8 * 4, 256, 0, stream>>>(Hs, WA, P, nullptr, nullptr,
                                                         SH_INTER, D_MODEL, 16, 8);

  // ---- routed experts (all 16 at once; ws is large) ----
  cvt_bf16_kernel<<<8192, 256, 0, stream>>>(W1, WA, 16 * N_INTER * D_MODEL / 4);
  cvt_bf16_kernel<<<8192, 256, 0, stream>>>(W3, WB, 16 * N_INTER * D_MODEL / 4);
  // fused G+U+SwiGLU -> Hr[slot] : grid 16x11x16 = 2816, active ~704 @ 2/CU
  gemm_gu2_kernel<1><<<16 * 11 * 16, 256, 0, stream>>>(xbf, WA, WB, Hr, list, cnt,
                                                       D_MODEL, N_INTER, 16, 11);
  cvt_bf16_kernel<<<8192, 256, 0, stream>>>(W2, WA, 16 * D_MODEL * N_INTER / 4);
  // routed down -> H2[slot] : grid 16x8x16 = 2048
  gemm_down_kernel<1, 1><<<16 * 8 * 16, 256, 0, stream>>>(Hr, WA, H2, list, cnt,
                                                          N_INTER, D_MODEL, 16, 8);
  combine_kernel<<<T_TOK, 256, 0, stream>>>(H2, P, wslot, out);
}